// Round 5
// baseline (1174.609 us; speedup 1.0000x reference)
//
#include <hip/hip_runtime.h>
#include <math.h>

#define DD 64
#define HH 128
#define SCHUNK 2048
#define BCHUNK 8192

typedef __attribute__((ext_vector_type(8))) short bf16x8;
typedef __attribute__((ext_vector_type(4))) short s16x4;
typedef __attribute__((ext_vector_type(4))) float f32x4;
typedef __attribute__((ext_vector_type(4))) int i32x4;

__device__ __forceinline__ short f2bf(float x){
    unsigned u = __builtin_bit_cast(unsigned, x);
    u += 0x7fffu + ((u >> 16) & 1u);          // RTNE
    return (short)(u >> 16);
}
__device__ __forceinline__ float bf2f(short s){
    unsigned u = ((unsigned)(unsigned short)s) << 16;
    return __builtin_bit_cast(float, u);
}
__device__ __forceinline__ float fast_tanh(float x){
    float e = __expf(2.0f * x);
    return 1.0f - 2.0f / (e + 1.0f);
}
__device__ __forceinline__ float elu1(float x){
    return x > 0.0f ? x : (__expf(x) - 1.0f);
}

// histogram of dst (int) for both graphs + h -> bf16 conversion
__global__ __launch_bounds__(256) void hist_conv(
    const int* __restrict__ dst1, const int* __restrict__ dst2,
    const float* __restrict__ h,
    int* __restrict__ cnt1, int* __restrict__ cnt2,
    short* __restrict__ h_bf, int E, int Nq) {
    int tid = blockIdx.x * 256 + threadIdx.x;
    if (tid < E) {
        atomicAdd(&cnt1[dst1[tid]], 1);
        atomicAdd(&cnt2[dst2[tid]], 1);
    }
    if (tid < Nq) {
        float4 v = ((const float4*)h)[tid];
        s16x4 o;
        o[0] = f2bf(v.x); o[1] = f2bf(v.y); o[2] = f2bf(v.z); o[3] = f2bf(v.w);
        ((s16x4*)h_bf)[tid] = o;
    }
}

// ---- 3-phase exclusive scan over both graphs' histograms ----
__global__ __launch_bounds__(256) void scan_reduce(
    const int* __restrict__ c1, const int* __restrict__ c2,
    int* __restrict__ part, int n, int nch) {
    int b = blockIdx.x;
    int g = b >= nch;
    const int* cnt = g ? c2 : c1;
    int cb = b - g * nch;
    int n4 = n >> 2;
    int i4 = cb * (SCHUNK / 4) + threadIdx.x * 2;
    int s = 0;
    #pragma unroll
    for (int k = 0; k < 2; k++) {
        if (i4 + k < n4) {
            int4 v = ((const int4*)cnt)[i4 + k];
            s += v.x + v.y + v.z + v.w;
        }
    }
    #pragma unroll
    for (int off = 32; off >= 1; off >>= 1) s += __shfl_xor(s, off, 64);
    __shared__ int red[4];
    int wv = threadIdx.x >> 6;
    if ((threadIdx.x & 63) == 0) red[wv] = s;
    __syncthreads();
    if (threadIdx.x == 0) part[b] = red[0] + red[1] + red[2] + red[3];
}

__global__ void scan_mid(int* __restrict__ part, int nch) {
    int t = threadIdx.x;
    if (t < 2) {
        int* p = part + t * nch;
        int run = 0;
        for (int i = 0; i < nch; i++) { int v = p[i]; p[i] = run; run += v; }
    }
}

__global__ __launch_bounds__(256) void scan_final(
    const int* __restrict__ c1, int* __restrict__ o1,
    const int* __restrict__ c2, int* __restrict__ o2,
    const int* __restrict__ part, int n, int nch) {
    int b = blockIdx.x;
    int g = b >= nch;
    const int* cnt = g ? c2 : c1;
    int* off       = g ? o2 : o1;
    int cb = b - g * nch;
    int n4 = n >> 2;
    int i4 = cb * (SCHUNK / 4) + threadIdx.x * 2;
    int4 v0 = {0,0,0,0}, v1 = {0,0,0,0};
    if (i4 < n4)     v0 = ((const int4*)cnt)[i4];
    if (i4 + 1 < n4) v1 = ((const int4*)cnt)[i4 + 1];
    int s = v0.x+v0.y+v0.z+v0.w + v1.x+v1.y+v1.z+v1.w;

    __shared__ int ssum[256];
    int tid = threadIdx.x;
    ssum[tid] = s;
    __syncthreads();
    for (int d = 1; d < 256; d <<= 1) {
        int t = (tid >= d) ? ssum[tid - d] : 0;
        __syncthreads();
        ssum[tid] += t;
        __syncthreads();
    }
    int run = part[b] + ssum[tid] - s;

    int4 o0, o1v;
    o0.x = run; run += v0.x;
    o0.y = run; run += v0.y;
    o0.z = run; run += v0.z;
    o0.w = run; run += v0.w;
    o1v.x = run; run += v1.x;
    o1v.y = run; run += v1.y;
    o1v.z = run; run += v1.z;
    o1v.w = run; run += v1.w;
    if (i4 < n4)     ((int4*)off)[i4]     = o0;
    if (i4 + 1 < n4) ((int4*)off)[i4 + 1] = o1v;
}

// per-bucket write cursors = off[b*256]
__global__ __launch_bounds__(256) void bucket_init(
    const int* __restrict__ off1, const int* __restrict__ off2,
    int* __restrict__ bcur1, int* __restrict__ bcur2, int NB) {
    int b = blockIdx.x * 256 + threadIdx.x;
    if (b < NB) {
        bcur1[b] = off1[b << 8];
        bcur2[b] = off2[b << 8];
    }
}

// bucketed counting sort: block = 8192-edge chunk; LDS bin by (dst>>8); flush
// contiguous per-bucket runs. packed edge = (src<<8) | (dst&255).
__global__ __launch_bounds__(256) void binsort(
    const int* __restrict__ src1, const int* __restrict__ dst1,
    const int* __restrict__ src2, const int* __restrict__ dst2,
    int* __restrict__ bcur1, int* __restrict__ bcur2,
    unsigned* __restrict__ ebuf1, unsigned* __restrict__ ebuf2,
    int E, int nch)
{
    __shared__ int sHist[1024];        // counts, then reused as place-cursors
    __shared__ int sBase[1025];        // exclusive prefix (staging base)
    __shared__ int sGb[1024];          // global base per bucket
    __shared__ unsigned sStage[BCHUNK];
    __shared__ int sTS[256];

    int bc = blockIdx.x;
    int g = bc >= nch;
    int chunk = bc - g * nch;
    const int* src = g ? src2 : src1;
    const int* dst = g ? dst2 : dst1;
    int* bcur      = g ? bcur2 : bcur1;
    unsigned* ebuf = g ? ebuf2 : ebuf1;
    int e0 = chunk * BCHUNK;
    int elen = E - e0; if (elen > BCHUNK) elen = BCHUNK;

    int tid = threadIdx.x;
    for (int i = tid; i < 1024; i += 256) sHist[i] = 0;
    __syncthreads();
    for (int j = tid; j < elen; j += 256)
        atomicAdd(&sHist[dst[e0 + j] >> 8], 1);
    __syncthreads();

    // block scan (thread owns 4 contiguous counters)
    int a0 = sHist[4*tid], a1 = sHist[4*tid+1], a2 = sHist[4*tid+2], a3 = sHist[4*tid+3];
    int s = a0 + a1 + a2 + a3;
    sTS[tid] = s;
    __syncthreads();
    for (int d = 1; d < 256; d <<= 1) {
        int t = (tid >= d) ? sTS[tid - d] : 0;
        __syncthreads();
        sTS[tid] += t;
        __syncthreads();
    }
    int run = sTS[tid] - s;
    sBase[4*tid]   = run; run += a0;
    sBase[4*tid+1] = run; run += a1;
    sBase[4*tid+2] = run; run += a2;
    sBase[4*tid+3] = run; run += a3;
    if (tid == 255) sBase[1024] = run;
    __syncthreads();

    // reserve global space, reset cursors
    for (int b = tid; b < 1024; b += 256) {
        int cnt = sBase[b+1] - sBase[b];
        sHist[b] = 0;
        if (cnt > 0) sGb[b] = atomicAdd(&bcur[b], cnt);
    }
    __syncthreads();

    // place into staging
    for (int j = tid; j < elen; j += 256) {
        int d = dst[e0 + j];
        int sr = src[e0 + j];
        int b = d >> 8;
        int pos = atomicAdd(&sHist[b], 1);
        sStage[sBase[b] + pos] = ((unsigned)sr << 8) | (unsigned)(d & 255);
    }
    __syncthreads();

    // flush contiguous runs
    int wv = tid >> 6, lane = tid & 63;
    for (int b = wv; b < 1024; b += 4) {
        int cnt = sBase[b+1] - sBase[b];
        if (cnt <= 0) continue;
        int gb = sGb[b], sb = sBase[b];
        for (int j = lane; j < cnt; j += 64)
            ebuf[gb + j] = sStage[sb + j];
    }
}

// block per (graph,bucket): accumulate h_bf rows into 64KB LDS f32, write bf16 rows
__global__ __launch_bounds__(256) void agg(
    const short* __restrict__ h_bf,
    const int* __restrict__ cnt1, const int* __restrict__ off1,
    const unsigned* __restrict__ ebuf1, short* __restrict__ a1bf,
    const int* __restrict__ cnt2, const int* __restrict__ off2,
    const unsigned* __restrict__ ebuf2, short* __restrict__ a2bf,
    int N, int NB, int E)
{
    __shared__ float sAcc[256 * DD];   // 64 KB
    int bid = blockIdx.x;
    int g = bid >= NB;
    int sb = bid - g * NB;
    const int* cnt       = g ? cnt2  : cnt1;
    const int* off       = g ? off2  : off1;
    const unsigned* ebuf = g ? ebuf2 : ebuf1;
    short* abf           = g ? a2bf  : a1bf;

    int tid = threadIdx.x;
    for (int i = tid; i < 256 * DD; i += 256) sAcc[i] = 0.f;

    int start = off[sb << 8];
    int nodeEnd = (sb + 1) << 8;
    int end = nodeEnd >= N ? E : off[nodeEnd];
    __syncthreads();

    int wv = tid >> 6, lane = tid & 63;
    int half = lane >> 5, hl = lane & 31;
    for (int e = start + wv * 2 + half; e < end; e += 8) {
        unsigned v = ebuf[e];
        int dl = v & 255;
        int sr = v >> 8;
        unsigned hw = ((const unsigned*)h_bf)[(size_t)sr * 32 + hl];
        float f0 = bf2f((short)(hw & 0xffff));
        float f1 = bf2f((short)(hw >> 16));
        atomicAdd(&sAcc[dl * DD + hl * 2],     f0);
        atomicAdd(&sAcc[dl * DD + hl * 2 + 1], f1);
    }
    __syncthreads();

    // epilogue: scale by 1/deg, write bf16 rows (half-wave per node)
    for (int k = 0; k < 32; k++) {
        int nl = wv * 64 + k * 2 + half;
        int node = (sb << 8) + nl;
        if (node < N) {
            int dg = cnt[node];
            float inv = dg > 0 ? 1.f / (float)dg : 0.f;
            float f0 = sAcc[nl * DD + hl * 2] * inv;
            float f1 = sAcc[nl * DD + hl * 2 + 1] * inv;
            unsigned o = (unsigned)(unsigned short)f2bf(f0)
                       | ((unsigned)(unsigned short)f2bf(f1) << 16);
            ((unsigned*)abf)[(size_t)node * 32 + hl] = o;
        }
    }
}

// MFMA fused kernel: wave = 16 nodes, block = 64 nodes, persistent grid.
__global__ __launch_bounds__(256, 2) void fuse_kernel(
    const short* __restrict__ h_bf,
    const float* __restrict__ W_id, const float* __restrict__ b_id,
    const float* __restrict__ W1, const float* __restrict__ b1,
    const float* __restrict__ W2, const float* __restrict__ b2,
    const float* __restrict__ Wp1, const float* __restrict__ bp1,
    const float* __restrict__ Wp2,
    const short* __restrict__ a1bf, const short* __restrict__ a2bf,
    short* __restrict__ zbuf1, short* __restrict__ zbuf2,
    float* __restrict__ w_acc, int N)
{
    __shared__ __align__(16) short sWb[12288];
    __shared__ __align__(16) short sWp[8192];
    __shared__ __align__(16) short sZ[4][3072];

    for (int i = threadIdx.x; i < 12288; i += 256) {
        int p = i >> 12, r = i & 4095;
        int ct = r >> 10, rr = r & 1023;
        int ks = rr >> 9, q = rr & 511;
        int ln = q >> 3, j = q & 7;
        int c = ct * 16 + (ln & 15);
        int k = ks * 32 + (ln >> 4) * 8 + j;
        int idx = k * DD + c;
        float v = (p == 0) ? W_id[idx] : (p == 1 ? W1[idx] : W2[idx]);
        sWb[i] = f2bf(v);
    }
    for (int i = threadIdx.x; i < 8192; i += 256) {
        int ct = i >> 10, rr = i & 1023;
        int ks = rr >> 9, q = rr & 511;
        int ln = q >> 3, j = q & 7;
        int c = ct * 16 + (ln & 15);
        int k = ks * 32 + (ln >> 4) * 8 + j;
        sWp[i] = f2bf(Wp1[k * HH + c]);
    }

    int lane = threadIdx.x & 63;
    int wv = threadIdx.x >> 6;
    int cl = lane & 15;
    int quad = lane >> 4;

    float bid[4], bb1r[4], bb2r[4];
    #pragma unroll
    for (int ct = 0; ct < 4; ct++) {
        bid[ct]  = b_id[ct*16 + cl];
        bb1r[ct] = b1[ct*16 + cl];
        bb2r[ct] = b2[ct*16 + cl];
    }
    float bpr[8], wp2r[8];
    #pragma unroll
    for (int ct = 0; ct < 8; ct++) {
        bpr[ct]  = bp1[ct*16 + cl];
        wp2r[ct] = Wp2[ct*16 + cl];
    }
    __syncthreads();

    float wsp0 = 0.f, wsp1 = 0.f, wsp2 = 0.f;
    int ntiles = (N + 63) >> 6;
    short* zw = sZ[wv];

    for (int tile = blockIdx.x; tile < ntiles; tile += gridDim.x) {
        int nb = tile * 64 + wv * 16;
        int arow = nb + cl;
        int arowc = arow < N ? arow : N - 1;

        f32x4 acc[3][4];
        #pragma unroll
        for (int p = 0; p < 3; p++)
            #pragma unroll
            for (int ct = 0; ct < 4; ct++)
                acc[p][ct] = (f32x4){0.f,0.f,0.f,0.f};

        #pragma unroll
        for (int ks = 0; ks < 2; ks++) {
            int kb = ks*32 + quad*8;
            bf16x8 fa0 = *(const bf16x8*)&h_bf[(size_t)arowc*DD + kb];
            bf16x8 fa1 = *(const bf16x8*)&a1bf[(size_t)arowc*DD + kb];
            bf16x8 fa2 = *(const bf16x8*)&a2bf[(size_t)arowc*DD + kb];
            #pragma unroll
            for (int ct = 0; ct < 4; ct++) {
                bf16x8 w0 = *(const bf16x8*)&sWb[        (ct*2+ks)*512 + lane*8];
                bf16x8 w1 = *(const bf16x8*)&sWb[4096 +  (ct*2+ks)*512 + lane*8];
                bf16x8 w2 = *(const bf16x8*)&sWb[8192 +  (ct*2+ks)*512 + lane*8];
                acc[0][ct] = __builtin_amdgcn_mfma_f32_16x16x32_bf16(fa0, w0, acc[0][ct], 0,0,0);
                acc[1][ct] = __builtin_amdgcn_mfma_f32_16x16x32_bf16(fa1, w1, acc[1][ct], 0,0,0);
                acc[2][ct] = __builtin_amdgcn_mfma_f32_16x16x32_bf16(fa2, w2, acc[2][ct], 0,0,0);
            }
        }

        #pragma unroll
        for (int ct = 0; ct < 4; ct++) {
            int c = ct*16 + cl;
            int obase = (c >> 5)*512 + ((c >> 3) & 3)*128 + (c & 7);
            #pragma unroll
            for (int r = 0; r < 4; r++) {
                int m = quad*4 + r;
                int off = obase + m*8;
                float z0 = acc[0][ct][r] + bid[ct];
                float z1 = elu1(acc[1][ct][r] + bb1r[ct]);
                float z2 = elu1(acc[2][ct][r] + bb2r[ct]);
                zw[off]        = f2bf(z0);
                zw[1024 + off] = f2bf(z1);
                zw[2048 + off] = f2bf(z2);
            }
        }

        float rmask[4];
        #pragma unroll
        for (int r = 0; r < 4; r++)
            rmask[r] = (nb + quad*4 + r) < N ? 1.f : 0.f;

        #pragma unroll
        for (int p = 0; p < 3; p++) {
            bf16x8 zA = *(const bf16x8*)&zw[p*1024 +       lane*8];
            bf16x8 zB = *(const bf16x8*)&zw[p*1024 + 512 + lane*8];
            float wsum = 0.f;
            #pragma unroll
            for (int ct = 0; ct < 8; ct++) {
                f32x4 t = (f32x4){0.f,0.f,0.f,0.f};
                bf16x8 u0 = *(const bf16x8*)&sWp[(ct*2+0)*512 + lane*8];
                bf16x8 u1 = *(const bf16x8*)&sWp[(ct*2+1)*512 + lane*8];
                t = __builtin_amdgcn_mfma_f32_16x16x32_bf16(zA, u0, t, 0,0,0);
                t = __builtin_amdgcn_mfma_f32_16x16x32_bf16(zB, u1, t, 0,0,0);
                float s = 0.f;
                #pragma unroll
                for (int r = 0; r < 4; r++)
                    s += fast_tanh(t[r] + bpr[ct]) * rmask[r];
                wsum += s * wp2r[ct];
            }
            if (p == 0)      wsp0 += wsum;
            else if (p == 1) wsp1 += wsum;
            else             wsp2 += wsum;
        }

        int m8 = lane >> 3;
        int q3 = lane & 7;
        int ks2 = q3 >> 2, qq = q3 & 3;
        #pragma unroll
        for (int pass = 0; pass < 2; pass++) {
            int m = pass*8 + m8;
            int node = nb + m;
            if (node < N) {
                int lo = ks2*512 + (m + qq*16)*8;
                i32x4 v0 = *(const i32x4*)&zw[lo];
                i32x4 v1 = *(const i32x4*)&zw[1024 + lo];
                i32x4 v2 = *(const i32x4*)&zw[2048 + lo];
                char* base1 = (char*)zbuf1 + (size_t)node*256 + ks2*64 + qq*16;
                *(i32x4*)base1 = v1;
                *(i32x4*)(base1 + 128) = v0;
                char* base2 = (char*)zbuf2 + (size_t)node*128 + ks2*64 + qq*16;
                *(i32x4*)base2 = v2;
            }
        }
    }

    #pragma unroll
    for (int off = 32; off >= 1; off >>= 1) {
        wsp0 += __shfl_xor(wsp0, off, 64);
        wsp1 += __shfl_xor(wsp1, off, 64);
        wsp2 += __shfl_xor(wsp2, off, 64);
    }
    if (lane == 0) {
        atomicAdd(&w_acc[0], wsp0);
        atomicAdd(&w_acc[1], wsp1);
        atomicAdd(&w_acc[2], wsp2);
    }
}

__global__ __launch_bounds__(256) void out_kernel(
    const short* __restrict__ zbuf1, const short* __restrict__ zbuf2,
    const float* __restrict__ w_acc, float* __restrict__ out,
    int N, float invN)
{
    int tid = blockIdx.x * 256 + threadIdx.x;
    int n = tid >> 3, part = tid & 7;
    if (n >= N) return;
    float w0 = w_acc[0]*invN, w1 = w_acc[1]*invN, w2 = w_acc[2]*invN;
    float m = fmaxf(w0, fmaxf(w1, w2));
    float e0 = __expf(w0-m), e1 = __expf(w1-m), e2 = __expf(w2-m);
    float s = 1.f/(e0+e1+e2);
    float beta0 = e0*s, beta1 = e1*s, beta2 = e2*s;

    const char* r1 = (const char*)zbuf1 + (size_t)n*256 + part*16;
    const char* r2 = (const char*)zbuf2 + (size_t)n*128 + part*16;
    union U { i32x4 v; short sh[8]; };
    U z1u, z0u, z2u;
    z1u.v = *(const i32x4*)r1;
    z0u.v = *(const i32x4*)(r1 + 128);
    z2u.v = *(const i32x4*)r2;
    float tmp[8];
    #pragma unroll
    for (int j = 0; j < 8; j++)
        tmp[j] = beta0*bf2f(z0u.sh[j]) + beta1*bf2f(z1u.sh[j]) + beta2*bf2f(z2u.sh[j]);
    float4* op = (float4*)(out + (size_t)n*64 + part*8);
    op[0] = (float4){tmp[0],tmp[1],tmp[2],tmp[3]};
    op[1] = (float4){tmp[4],tmp[5],tmp[6],tmp[7]};
}

extern "C" void kernel_launch(void* const* d_in, const int* in_sizes, int n_in,
                              void* d_out, int out_size, void* d_ws, size_t ws_size,
                              hipStream_t stream) {
    const float* h    = (const float*)d_in[0];
    const int*   src1 = (const int*)d_in[1];
    const int*   dst1 = (const int*)d_in[2];
    const int*   src2 = (const int*)d_in[3];
    const int*   dst2 = (const int*)d_in[4];
    const float* W_id = (const float*)d_in[5];
    const float* b_id = (const float*)d_in[6];
    const float* W1   = (const float*)d_in[7];
    const float* b1   = (const float*)d_in[8];
    const float* W2   = (const float*)d_in[9];
    const float* b2   = (const float*)d_in[10];
    const float* Wp1  = (const float*)d_in[11];
    const float* bp1  = (const float*)d_in[12];
    const float* Wp2  = (const float*)d_in[13];
    float* out = (float*)d_out;

    int N = in_sizes[0] / DD;
    int E = in_sizes[1];
    int nch = (N + SCHUNK - 1) / SCHUNK;
    int NB  = (N + 255) >> 8;

    char* p = (char*)d_ws;
    int*   cnt1  = (int*)p;   p += (size_t)N * 4;
    int*   cnt2  = (int*)p;   p += (size_t)N * 4;
    float* w_acc = (float*)p; p += 32;
    int*   part  = (int*)p;   p += (size_t)2 * nch * 4;
    int*   off1  = (int*)p;   p += (size_t)N * 4;
    int*   off2  = (int*)p;   p += (size_t)N * 4;
    int*   bcur1 = (int*)p;   p += (size_t)1024 * 4;
    int*   bcur2 = (int*)p;   p += (size_t)1024 * 4;
    unsigned* ebuf1 = (unsigned*)p; p += (size_t)E * 4;
    unsigned* ebuf2 = (unsigned*)p; p += (size_t)E * 4;
    short* h_bf  = (short*)p; p += (size_t)N * DD * 2;
    short* a1bf  = (short*)p; p += (size_t)N * DD * 2;
    short* a2bf  = (short*)p; p += (size_t)N * DD * 2;
    short* zbuf1 = (short*)p; p += (size_t)N * 128 * 2;
    short* zbuf2 = (short*)p; p += (size_t)N * DD * 2;

    hipMemsetAsync(d_ws, 0, (size_t)2 * N * 4 + 32, stream);

    int Nq = N * 16;
    int hc_threads = Nq > E ? Nq : E;
    hist_conv<<<(hc_threads + 255) / 256, 256, 0, stream>>>(
        dst1, dst2, h, cnt1, cnt2, h_bf, E, Nq);

    scan_reduce<<<2 * nch, 256, 0, stream>>>(cnt1, cnt2, part, N, nch);
    scan_mid<<<1, 64, 0, stream>>>(part, nch);
    scan_final<<<2 * nch, 256, 0, stream>>>(cnt1, off1, cnt2, off2, part, N, nch);

    bucket_init<<<(NB + 255) / 256, 256, 0, stream>>>(off1, off2, bcur1, bcur2, NB);

    int nech = (E + BCHUNK - 1) / BCHUNK;
    binsort<<<2 * nech, 256, 0, stream>>>(src1, dst1, src2, dst2,
                                          bcur1, bcur2, ebuf1, ebuf2, E, nech);

    agg<<<2 * NB, 256, 0, stream>>>(h_bf,
                                    cnt1, off1, ebuf1, a1bf,
                                    cnt2, off2, ebuf2, a2bf, N, NB, E);

    int ntiles = (N + 63) >> 6;
    int fblocks = ntiles < 512 ? ntiles : 512;
    fuse_kernel<<<fblocks, 256, 0, stream>>>(h_bf, W_id, b_id, W1, b1, W2, b2,
                                             Wp1, bp1, Wp2, a1bf, a2bf,
                                             zbuf1, zbuf2, w_acc, N);

    out_kernel<<<(N * 8 + 255) / 256, 256, 0, stream>>>(zbuf1, zbuf2, w_acc, out, N, 1.0f / (float)N);
}

// Round 6
// 605.091 us; speedup vs baseline: 1.9412x; 1.9412x over previous
//
#include <hip/hip_runtime.h>
#include <math.h>

#define DD 64
#define HH 128
#define SCHUNK 2048
#define BCHUNK 8192

typedef __attribute__((ext_vector_type(8))) short bf16x8;
typedef __attribute__((ext_vector_type(4))) short s16x4;
typedef __attribute__((ext_vector_type(4))) float f32x4;
typedef __attribute__((ext_vector_type(4))) int i32x4;

__device__ __forceinline__ short f2bf(float x){
    unsigned u = __builtin_bit_cast(unsigned, x);
    u += 0x7fffu + ((u >> 16) & 1u);          // RTNE
    return (short)(u >> 16);
}
__device__ __forceinline__ float bf2f(short s){
    unsigned u = ((unsigned)(unsigned short)s) << 16;
    return __builtin_bit_cast(float, u);
}
__device__ __forceinline__ float fast_tanh(float x){
    float e = __expf(2.0f * x);
    return 1.0f - 2.0f / (e + 1.0f);
}
__device__ __forceinline__ float elu1(float x){
    return x > 0.0f ? x : (__expf(x) - 1.0f);
}

// histogram of dst (int) for both graphs + h -> bf16 conversion
__global__ __launch_bounds__(256) void hist_conv(
    const int* __restrict__ dst1, const int* __restrict__ dst2,
    const float* __restrict__ h,
    int* __restrict__ cnt1, int* __restrict__ cnt2,
    short* __restrict__ h_bf, int E, int Nq) {
    int tid = blockIdx.x * 256 + threadIdx.x;
    if (tid < E) {
        atomicAdd(&cnt1[dst1[tid]], 1);
        atomicAdd(&cnt2[dst2[tid]], 1);
    }
    if (tid < Nq) {
        float4 v = ((const float4*)h)[tid];
        s16x4 o;
        o[0] = f2bf(v.x); o[1] = f2bf(v.y); o[2] = f2bf(v.z); o[3] = f2bf(v.w);
        ((s16x4*)h_bf)[tid] = o;
    }
}

// ---- 3-phase exclusive scan over both graphs' histograms ----
__global__ __launch_bounds__(256) void scan_reduce(
    const int* __restrict__ c1, const int* __restrict__ c2,
    int* __restrict__ part, int n, int nch) {
    int b = blockIdx.x;
    int g = b >= nch;
    const int* cnt = g ? c2 : c1;
    int cb = b - g * nch;
    int n4 = n >> 2;
    int i4 = cb * (SCHUNK / 4) + threadIdx.x * 2;
    int s = 0;
    #pragma unroll
    for (int k = 0; k < 2; k++) {
        if (i4 + k < n4) {
            int4 v = ((const int4*)cnt)[i4 + k];
            s += v.x + v.y + v.z + v.w;
        }
    }
    #pragma unroll
    for (int off = 32; off >= 1; off >>= 1) s += __shfl_xor(s, off, 64);
    __shared__ int red[4];
    int wv = threadIdx.x >> 6;
    if ((threadIdx.x & 63) == 0) red[wv] = s;
    __syncthreads();
    if (threadIdx.x == 0) part[b] = red[0] + red[1] + red[2] + red[3];
}

__global__ void scan_mid(int* __restrict__ part, int nch) {
    int t = threadIdx.x;
    if (t < 2) {
        int* p = part + t * nch;
        int run = 0;
        for (int i = 0; i < nch; i++) { int v = p[i]; p[i] = run; run += v; }
    }
}

__global__ __launch_bounds__(256) void scan_final(
    const int* __restrict__ c1, int* __restrict__ o1,
    const int* __restrict__ c2, int* __restrict__ o2,
    const int* __restrict__ part, int n, int nch) {
    int b = blockIdx.x;
    int g = b >= nch;
    const int* cnt = g ? c2 : c1;
    int* off       = g ? o2 : o1;
    int cb = b - g * nch;
    int n4 = n >> 2;
    int i4 = cb * (SCHUNK / 4) + threadIdx.x * 2;
    int4 v0 = {0,0,0,0}, v1 = {0,0,0,0};
    if (i4 < n4)     v0 = ((const int4*)cnt)[i4];
    if (i4 + 1 < n4) v1 = ((const int4*)cnt)[i4 + 1];
    int s = v0.x+v0.y+v0.z+v0.w + v1.x+v1.y+v1.z+v1.w;

    __shared__ int ssum[256];
    int tid = threadIdx.x;
    ssum[tid] = s;
    __syncthreads();
    for (int d = 1; d < 256; d <<= 1) {
        int t = (tid >= d) ? ssum[tid - d] : 0;
        __syncthreads();
        ssum[tid] += t;
        __syncthreads();
    }
    int run = part[b] + ssum[tid] - s;

    int4 o0, o1v;
    o0.x = run; run += v0.x;
    o0.y = run; run += v0.y;
    o0.z = run; run += v0.z;
    o0.w = run; run += v0.w;
    o1v.x = run; run += v1.x;
    o1v.y = run; run += v1.y;
    o1v.z = run; run += v1.z;
    o1v.w = run; run += v1.w;
    if (i4 < n4)     ((int4*)off)[i4]     = o0;
    if (i4 + 1 < n4) ((int4*)off)[i4 + 1] = o1v;
}

// per-bucket write cursors = off[b*256]
__global__ __launch_bounds__(256) void bucket_init(
    const int* __restrict__ off1, const int* __restrict__ off2,
    int* __restrict__ bcur1, int* __restrict__ bcur2, int NB) {
    int b = blockIdx.x * 256 + threadIdx.x;
    if (b < NB) {
        bcur1[b] = off1[b << 8];
        bcur2[b] = off2[b << 8];
    }
}

// bucketed counting sort: block = 8192-edge chunk; LDS bin by (dst>>8); flush
// contiguous per-bucket runs. packed edge = (src<<8) | (dst&255).
__global__ __launch_bounds__(256) void binsort(
    const int* __restrict__ src1, const int* __restrict__ dst1,
    const int* __restrict__ src2, const int* __restrict__ dst2,
    int* __restrict__ bcur1, int* __restrict__ bcur2,
    unsigned* __restrict__ ebuf1, unsigned* __restrict__ ebuf2,
    int E, int nch)
{
    __shared__ int sHist[1024];
    __shared__ int sBase[1025];
    __shared__ int sGb[1024];
    __shared__ unsigned sStage[BCHUNK];
    __shared__ int sTS[256];

    int bc = blockIdx.x;
    int g = bc >= nch;
    int chunk = bc - g * nch;
    const int* src = g ? src2 : src1;
    const int* dst = g ? dst2 : dst1;
    int* bcur      = g ? bcur2 : bcur1;
    unsigned* ebuf = g ? ebuf2 : ebuf1;
    int e0 = chunk * BCHUNK;
    int elen = E - e0; if (elen > BCHUNK) elen = BCHUNK;

    int tid = threadIdx.x;
    for (int i = tid; i < 1024; i += 256) sHist[i] = 0;
    __syncthreads();
    for (int j = tid; j < elen; j += 256)
        atomicAdd(&sHist[dst[e0 + j] >> 8], 1);
    __syncthreads();

    int a0 = sHist[4*tid], a1 = sHist[4*tid+1], a2 = sHist[4*tid+2], a3 = sHist[4*tid+3];
    int s = a0 + a1 + a2 + a3;
    sTS[tid] = s;
    __syncthreads();
    for (int d = 1; d < 256; d <<= 1) {
        int t = (tid >= d) ? sTS[tid - d] : 0;
        __syncthreads();
        sTS[tid] += t;
        __syncthreads();
    }
    int run = sTS[tid] - s;
    sBase[4*tid]   = run; run += a0;
    sBase[4*tid+1] = run; run += a1;
    sBase[4*tid+2] = run; run += a2;
    sBase[4*tid+3] = run; run += a3;
    if (tid == 255) sBase[1024] = run;
    __syncthreads();

    for (int b = tid; b < 1024; b += 256) {
        int cnt = sBase[b+1] - sBase[b];
        sHist[b] = 0;
        if (cnt > 0) sGb[b] = atomicAdd(&bcur[b], cnt);
    }
    __syncthreads();

    for (int j = tid; j < elen; j += 256) {
        int d = dst[e0 + j];
        int sr = src[e0 + j];
        int b = d >> 8;
        int pos = atomicAdd(&sHist[b], 1);
        sStage[sBase[b] + pos] = ((unsigned)sr << 8) | (unsigned)(d & 255);
    }
    __syncthreads();

    int wv = tid >> 6, lane = tid & 63;
    for (int b = wv; b < 1024; b += 4) {
        int cnt = sBase[b+1] - sBase[b];
        if (cnt <= 0) continue;
        int gb = sGb[b], sb = sBase[b];
        for (int j = lane; j < cnt; j += 64)
            ebuf[gb + j] = sStage[sb + j];
    }
}

// within-bucket counting sort: block per (graph,bucket); scattered stores land
// in a ~5KB hot window -> L2 line reuse, ~8MB total HBM write.
__global__ __launch_bounds__(256) void bsort2(
    const unsigned* __restrict__ ebuf1, const unsigned* __restrict__ ebuf2,
    const int* __restrict__ off1, const int* __restrict__ off2,
    int* __restrict__ eidx1, int* __restrict__ eidx2,
    int N, int NB, int E)
{
    __shared__ int sHist[256];
    __shared__ int sBase[256];
    __shared__ int sCur[256];
    __shared__ int sTS[256];

    int bid = blockIdx.x;
    int g = bid >= NB;
    int sb = bid - g * NB;
    const unsigned* ebuf = g ? ebuf2 : ebuf1;
    const int* off       = g ? off2  : off1;
    int* eidx            = g ? eidx2 : eidx1;

    int segBase = off[sb << 8];
    int nodeEnd = (sb + 1) << 8;
    int end = nodeEnd >= N ? E : off[nodeEnd];
    int len = end - segBase;

    int tid = threadIdx.x;
    sHist[tid] = 0;
    __syncthreads();
    for (int j = tid; j < len; j += 256)
        atomicAdd(&sHist[ebuf[segBase + j] & 255], 1);
    __syncthreads();

    int s = sHist[tid];
    sTS[tid] = s;
    __syncthreads();
    for (int d = 1; d < 256; d <<= 1) {
        int t = (tid >= d) ? sTS[tid - d] : 0;
        __syncthreads();
        sTS[tid] += t;
        __syncthreads();
    }
    sBase[tid] = sTS[tid] - s;   // exclusive
    sCur[tid] = 0;
    __syncthreads();

    for (int j = tid; j < len; j += 256) {
        unsigned v = ebuf[segBase + j];
        int dl = v & 255;
        int pos = atomicAdd(&sCur[dl], 1);
        eidx[segBase + sBase[dl] + pos] = (int)(v >> 8);
    }
}

// wave per (graph,node): half-wave per edge, bf16 rows, register accumulation
__global__ __launch_bounds__(256) void gather(
    const unsigned* __restrict__ h_bf,
    const int* __restrict__ cnt1, const int* __restrict__ off1,
    const int* __restrict__ eidx1, unsigned* __restrict__ a1bf,
    const int* __restrict__ cnt2, const int* __restrict__ off2,
    const int* __restrict__ eidx2, unsigned* __restrict__ a2bf, int N) {
    int w = blockIdx.x * 4 + (threadIdx.x >> 6);
    int lane = threadIdx.x & 63;
    if (w >= 2 * N) return;
    int g = w >= N;
    int n = g ? w - N : w;
    const int* cnt  = g ? cnt2  : cnt1;
    const int* off  = g ? off2  : off1;
    const int* eidx = g ? eidx2 : eidx1;
    unsigned* abf   = g ? a2bf  : a1bf;

    int start = off[n];
    int deg = cnt[n];
    int end = start + deg;
    int half = lane >> 5, hl = lane & 31;

    float a0 = 0.f, a1 = 0.f;
    for (int e = start + half; e < end; e += 2) {
        int sr = eidx[e];
        unsigned hw = h_bf[(size_t)sr * 32 + hl];
        a0 += bf2f((short)(hw & 0xffff));
        a1 += bf2f((short)(hw >> 16));
    }
    a0 += __shfl_xor(a0, 32, 64);
    a1 += __shfl_xor(a1, 32, 64);
    if (half == 0) {
        float inv = deg > 0 ? 1.f / (float)deg : 0.f;
        unsigned o = (unsigned)(unsigned short)f2bf(a0 * inv)
                   | ((unsigned)(unsigned short)f2bf(a1 * inv) << 16);
        abf[(size_t)n * 32 + hl] = o;
    }
}

// MFMA fused kernel: wave = 16 nodes, block = 64 nodes, persistent grid.
__global__ __launch_bounds__(256, 2) void fuse_kernel(
    const short* __restrict__ h_bf,
    const float* __restrict__ W_id, const float* __restrict__ b_id,
    const float* __restrict__ W1, const float* __restrict__ b1,
    const float* __restrict__ W2, const float* __restrict__ b2,
    const float* __restrict__ Wp1, const float* __restrict__ bp1,
    const float* __restrict__ Wp2,
    const short* __restrict__ a1bf, const short* __restrict__ a2bf,
    short* __restrict__ zbuf1, short* __restrict__ zbuf2,
    float* __restrict__ w_acc, int N)
{
    __shared__ __align__(16) short sWb[12288];
    __shared__ __align__(16) short sWp[8192];
    __shared__ __align__(16) short sZ[4][3072];

    for (int i = threadIdx.x; i < 12288; i += 256) {
        int p = i >> 12, r = i & 4095;
        int ct = r >> 10, rr = r & 1023;
        int ks = rr >> 9, q = rr & 511;
        int ln = q >> 3, j = q & 7;
        int c = ct * 16 + (ln & 15);
        int k = ks * 32 + (ln >> 4) * 8 + j;
        int idx = k * DD + c;
        float v = (p == 0) ? W_id[idx] : (p == 1 ? W1[idx] : W2[idx]);
        sWb[i] = f2bf(v);
    }
    for (int i = threadIdx.x; i < 8192; i += 256) {
        int ct = i >> 10, rr = i & 1023;
        int ks = rr >> 9, q = rr & 511;
        int ln = q >> 3, j = q & 7;
        int c = ct * 16 + (ln & 15);
        int k = ks * 32 + (ln >> 4) * 8 + j;
        sWp[i] = f2bf(Wp1[k * HH + c]);
    }

    int lane = threadIdx.x & 63;
    int wv = threadIdx.x >> 6;
    int cl = lane & 15;
    int quad = lane >> 4;

    float bid[4], bb1r[4], bb2r[4];
    #pragma unroll
    for (int ct = 0; ct < 4; ct++) {
        bid[ct]  = b_id[ct*16 + cl];
        bb1r[ct] = b1[ct*16 + cl];
        bb2r[ct] = b2[ct*16 + cl];
    }
    float bpr[8], wp2r[8];
    #pragma unroll
    for (int ct = 0; ct < 8; ct++) {
        bpr[ct]  = bp1[ct*16 + cl];
        wp2r[ct] = Wp2[ct*16 + cl];
    }
    __syncthreads();

    float wsp0 = 0.f, wsp1 = 0.f, wsp2 = 0.f;
    int ntiles = (N + 63) >> 6;
    short* zw = sZ[wv];

    for (int tile = blockIdx.x; tile < ntiles; tile += gridDim.x) {
        int nb = tile * 64 + wv * 16;
        int arow = nb + cl;
        int arowc = arow < N ? arow : N - 1;

        f32x4 acc[3][4];
        #pragma unroll
        for (int p = 0; p < 3; p++)
            #pragma unroll
            for (int ct = 0; ct < 4; ct++)
                acc[p][ct] = (f32x4){0.f,0.f,0.f,0.f};

        #pragma unroll
        for (int ks = 0; ks < 2; ks++) {
            int kb = ks*32 + quad*8;
            bf16x8 fa0 = *(const bf16x8*)&h_bf[(size_t)arowc*DD + kb];
            bf16x8 fa1 = *(const bf16x8*)&a1bf[(size_t)arowc*DD + kb];
            bf16x8 fa2 = *(const bf16x8*)&a2bf[(size_t)arowc*DD + kb];
            #pragma unroll
            for (int ct = 0; ct < 4; ct++) {
                bf16x8 w0 = *(const bf16x8*)&sWb[        (ct*2+ks)*512 + lane*8];
                bf16x8 w1 = *(const bf16x8*)&sWb[4096 +  (ct*2+ks)*512 + lane*8];
                bf16x8 w2 = *(const bf16x8*)&sWb[8192 +  (ct*2+ks)*512 + lane*8];
                acc[0][ct] = __builtin_amdgcn_mfma_f32_16x16x32_bf16(fa0, w0, acc[0][ct], 0,0,0);
                acc[1][ct] = __builtin_amdgcn_mfma_f32_16x16x32_bf16(fa1, w1, acc[1][ct], 0,0,0);
                acc[2][ct] = __builtin_amdgcn_mfma_f32_16x16x32_bf16(fa2, w2, acc[2][ct], 0,0,0);
            }
        }

        #pragma unroll
        for (int ct = 0; ct < 4; ct++) {
            int c = ct*16 + cl;
            int obase = (c >> 5)*512 + ((c >> 3) & 3)*128 + (c & 7);
            #pragma unroll
            for (int r = 0; r < 4; r++) {
                int m = quad*4 + r;
                int off = obase + m*8;
                float z0 = acc[0][ct][r] + bid[ct];
                float z1 = elu1(acc[1][ct][r] + bb1r[ct]);
                float z2 = elu1(acc[2][ct][r] + bb2r[ct]);
                zw[off]        = f2bf(z0);
                zw[1024 + off] = f2bf(z1);
                zw[2048 + off] = f2bf(z2);
            }
        }

        float rmask[4];
        #pragma unroll
        for (int r = 0; r < 4; r++)
            rmask[r] = (nb + quad*4 + r) < N ? 1.f : 0.f;

        #pragma unroll
        for (int p = 0; p < 3; p++) {
            bf16x8 zA = *(const bf16x8*)&zw[p*1024 +       lane*8];
            bf16x8 zB = *(const bf16x8*)&zw[p*1024 + 512 + lane*8];
            float wsum = 0.f;
            #pragma unroll
            for (int ct = 0; ct < 8; ct++) {
                f32x4 t = (f32x4){0.f,0.f,0.f,0.f};
                bf16x8 u0 = *(const bf16x8*)&sWp[(ct*2+0)*512 + lane*8];
                bf16x8 u1 = *(const bf16x8*)&sWp[(ct*2+1)*512 + lane*8];
                t = __builtin_amdgcn_mfma_f32_16x16x32_bf16(zA, u0, t, 0,0,0);
                t = __builtin_amdgcn_mfma_f32_16x16x32_bf16(zB, u1, t, 0,0,0);
                float s = 0.f;
                #pragma unroll
                for (int r = 0; r < 4; r++)
                    s += fast_tanh(t[r] + bpr[ct]) * rmask[r];
                wsum += s * wp2r[ct];
            }
            if (p == 0)      wsp0 += wsum;
            else if (p == 1) wsp1 += wsum;
            else             wsp2 += wsum;
        }

        int m8 = lane >> 3;
        int q3 = lane & 7;
        int ks2 = q3 >> 2, qq = q3 & 3;
        #pragma unroll
        for (int pass = 0; pass < 2; pass++) {
            int m = pass*8 + m8;
            int node = nb + m;
            if (node < N) {
                int lo = ks2*512 + (m + qq*16)*8;
                i32x4 v0 = *(const i32x4*)&zw[lo];
                i32x4 v1 = *(const i32x4*)&zw[1024 + lo];
                i32x4 v2 = *(const i32x4*)&zw[2048 + lo];
                char* base1 = (char*)zbuf1 + (size_t)node*256 + ks2*64 + qq*16;
                *(i32x4*)base1 = v1;
                *(i32x4*)(base1 + 128) = v0;
                char* base2 = (char*)zbuf2 + (size_t)node*128 + ks2*64 + qq*16;
                *(i32x4*)base2 = v2;
            }
        }
    }

    #pragma unroll
    for (int off = 32; off >= 1; off >>= 1) {
        wsp0 += __shfl_xor(wsp0, off, 64);
        wsp1 += __shfl_xor(wsp1, off, 64);
        wsp2 += __shfl_xor(wsp2, off, 64);
    }
    if (lane == 0) {
        atomicAdd(&w_acc[0], wsp0);
        atomicAdd(&w_acc[1], wsp1);
        atomicAdd(&w_acc[2], wsp2);
    }
}

__global__ __launch_bounds__(256) void out_kernel(
    const short* __restrict__ zbuf1, const short* __restrict__ zbuf2,
    const float* __restrict__ w_acc, float* __restrict__ out,
    int N, float invN)
{
    int tid = blockIdx.x * 256 + threadIdx.x;
    int n = tid >> 3, part = tid & 7;
    if (n >= N) return;
    float w0 = w_acc[0]*invN, w1 = w_acc[1]*invN, w2 = w_acc[2]*invN;
    float m = fmaxf(w0, fmaxf(w1, w2));
    float e0 = __expf(w0-m), e1 = __expf(w1-m), e2 = __expf(w2-m);
    float s = 1.f/(e0+e1+e2);
    float beta0 = e0*s, beta1 = e1*s, beta2 = e2*s;

    const char* r1 = (const char*)zbuf1 + (size_t)n*256 + part*16;
    const char* r2 = (const char*)zbuf2 + (size_t)n*128 + part*16;
    union U { i32x4 v; short sh[8]; };
    U z1u, z0u, z2u;
    z1u.v = *(const i32x4*)r1;
    z0u.v = *(const i32x4*)(r1 + 128);
    z2u.v = *(const i32x4*)r2;
    float tmp[8];
    #pragma unroll
    for (int j = 0; j < 8; j++)
        tmp[j] = beta0*bf2f(z0u.sh[j]) + beta1*bf2f(z1u.sh[j]) + beta2*bf2f(z2u.sh[j]);
    float4* op = (float4*)(out + (size_t)n*64 + part*8);
    op[0] = (float4){tmp[0],tmp[1],tmp[2],tmp[3]};
    op[1] = (float4){tmp[4],tmp[5],tmp[6],tmp[7]};
}

extern "C" void kernel_launch(void* const* d_in, const int* in_sizes, int n_in,
                              void* d_out, int out_size, void* d_ws, size_t ws_size,
                              hipStream_t stream) {
    const float* h    = (const float*)d_in[0];
    const int*   src1 = (const int*)d_in[1];
    const int*   dst1 = (const int*)d_in[2];
    const int*   src2 = (const int*)d_in[3];
    const int*   dst2 = (const int*)d_in[4];
    const float* W_id = (const float*)d_in[5];
    const float* b_id = (const float*)d_in[6];
    const float* W1   = (const float*)d_in[7];
    const float* b1   = (const float*)d_in[8];
    const float* W2   = (const float*)d_in[9];
    const float* b2   = (const float*)d_in[10];
    const float* Wp1  = (const float*)d_in[11];
    const float* bp1  = (const float*)d_in[12];
    const float* Wp2  = (const float*)d_in[13];
    float* out = (float*)d_out;

    int N = in_sizes[0] / DD;
    int E = in_sizes[1];
    int nch = (N + SCHUNK - 1) / SCHUNK;
    int NB  = (N + 255) >> 8;

    char* p = (char*)d_ws;
    int*   cnt1  = (int*)p;   p += (size_t)N * 4;
    int*   cnt2  = (int*)p;   p += (size_t)N * 4;
    float* w_acc = (float*)p; p += 32;
    int*   part  = (int*)p;   p += (size_t)2 * nch * 4;
    int*   off1  = (int*)p;   p += (size_t)N * 4;
    int*   off2  = (int*)p;   p += (size_t)N * 4;
    int*   bcur1 = (int*)p;   p += (size_t)1024 * 4;
    int*   bcur2 = (int*)p;   p += (size_t)1024 * 4;
    unsigned* ebuf1 = (unsigned*)p; p += (size_t)E * 4;
    unsigned* ebuf2 = (unsigned*)p; p += (size_t)E * 4;
    int*   eidx1 = (int*)p;   p += (size_t)E * 4;
    int*   eidx2 = (int*)p;   p += (size_t)E * 4;
    short* h_bf  = (short*)p; p += (size_t)N * DD * 2;
    short* a1bf  = (short*)p; p += (size_t)N * DD * 2;
    short* a2bf  = (short*)p; p += (size_t)N * DD * 2;
    short* zbuf1 = (short*)p; p += (size_t)N * 128 * 2;
    short* zbuf2 = (short*)p; p += (size_t)N * DD * 2;

    hipMemsetAsync(d_ws, 0, (size_t)2 * N * 4 + 32, stream);

    int Nq = N * 16;
    int hc_threads = Nq > E ? Nq : E;
    hist_conv<<<(hc_threads + 255) / 256, 256, 0, stream>>>(
        dst1, dst2, h, cnt1, cnt2, h_bf, E, Nq);

    scan_reduce<<<2 * nch, 256, 0, stream>>>(cnt1, cnt2, part, N, nch);
    scan_mid<<<1, 64, 0, stream>>>(part, nch);
    scan_final<<<2 * nch, 256, 0, stream>>>(cnt1, off1, cnt2, off2, part, N, nch);

    bucket_init<<<(NB + 255) / 256, 256, 0, stream>>>(off1, off2, bcur1, bcur2, NB);

    int nech = (E + BCHUNK - 1) / BCHUNK;
    binsort<<<2 * nech, 256, 0, stream>>>(src1, dst1, src2, dst2,
                                          bcur1, bcur2, ebuf1, ebuf2, E, nech);

    bsort2<<<2 * NB, 256, 0, stream>>>(ebuf1, ebuf2, off1, off2,
                                       eidx1, eidx2, N, NB, E);

    gather<<<(2 * N + 3) / 4, 256, 0, stream>>>(
        (const unsigned*)h_bf, cnt1, off1, eidx1, (unsigned*)a1bf,
        cnt2, off2, eidx2, (unsigned*)a2bf, N);

    int ntiles = (N + 63) >> 6;
    int fblocks = ntiles < 512 ? ntiles : 512;
    fuse_kernel<<<fblocks, 256, 0, stream>>>(h_bf, W_id, b_id, W1, b1, W2, b2,
                                             Wp1, bp1, Wp2, a1bf, a2bf,
                                             zbuf1, zbuf2, w_acc, N);

    out_kernel<<<(N * 8 + 255) / 256, 256, 0, stream>>>(zbuf1, zbuf2, w_acc, out, N, 1.0f / (float)N);
}